// Round 1
// baseline (76.892 us; speedup 1.0000x reference)
//
#include <hip/hip_runtime.h>
#include <math.h>

// Problem shape (fixed by reference setup_inputs): B=1, N=4096 queries, F=4096 faces.
#define N_Q 4096
#define N_F 4096
#define FSPLIT 32           // face-dimension grid split -> 16 x 32 = 512 blocks
#define FT (N_F / FSPLIT)   // 128 faces per block, staged in LDS

__device__ __forceinline__ constexpr float inv_two_pi() { return 0.15915494309189535f; }

__global__ __launch_bounds__(256) void winding_kernel(
    const float* __restrict__ qp,   // [N_Q][3]
    const float* __restrict__ fc,   // [N_F][3][3] = [N_F][9]
    float* __restrict__ out)        // [N_Q]
{
    __shared__ float sf[FT * 9];

    const int q  = blockIdx.x * 256 + threadIdx.x;   // one query per thread
    const int f0 = blockIdx.y * FT;                  // this block's face slice

    // Cooperative stage of the face slice into LDS (128 faces * 9 floats = 4.5 KB)
    for (int i = threadIdx.x; i < FT * 9; i += 256)
        sf[i] = fc[f0 * 9 + i];
    __syncthreads();

    const float qx = qp[q * 3 + 0];
    const float qy = qp[q * 3 + 1];
    const float qz = qp[q * 3 + 2];

    float sum = 0.0f;
    #pragma unroll 2
    for (int f = 0; f < FT; ++f) {
        const float* v = &sf[f * 9];   // all lanes read same face -> LDS broadcast (free)
        const float ax = v[0] - qx, ay = v[1] - qy, az = v[2] - qz;
        const float bx = v[3] - qx, by = v[4] - qy, bz = v[5] - qz;
        const float cx = v[6] - qx, cy = v[7] - qy, cz = v[8] - qz;

        // det = a . (b x c)
        const float ux = by * cz - bz * cy;
        const float uy = bz * cx - bx * cz;
        const float uz = bx * cy - by * cx;
        const float det = ax * ux + ay * uy + az * uz;

        const float na = sqrtf(ax * ax + ay * ay + az * az);
        const float nb = sqrtf(bx * bx + by * by + bz * bz);
        const float nc = sqrtf(cx * cx + cy * cy + cz * cz);

        const float ab = ax * bx + ay * by + az * bz;
        const float bc = bx * cx + by * cy + bz * cz;
        const float ac = ax * cx + ay * cy + az * cz;

        const float denom = na * nb * nc + bc * na + ac * nb + ab * nc;
        sum += atan2f(det, denom);
    }

    atomicAdd(&out[q], sum * inv_two_pi());
}

extern "C" void kernel_launch(void* const* d_in, const int* in_sizes, int n_in,
                              void* d_out, int out_size, void* d_ws, size_t ws_size,
                              hipStream_t stream) {
    const float* qp = (const float*)d_in[0];   // query_points (1,4096,3) f32
    const float* fc = (const float*)d_in[1];   // face_coord   (1,4096,3,3) f32
    float* out = (float*)d_out;                // (1,4096) f32

    // Harness poisons d_out once and never re-poisons between replays:
    // we accumulate with atomics, so zero it ourselves every call.
    hipMemsetAsync(out, 0, (size_t)out_size * sizeof(float), stream);

    dim3 grid(N_Q / 256, FSPLIT);
    dim3 block(256);
    winding_kernel<<<grid, block, 0, stream>>>(qp, fc, out);
}

// Round 2
// 38.517 us; speedup vs baseline: 1.9963x; 1.9963x over previous
//
#include <hip/hip_runtime.h>
#include <math.h>

// B=1, N=4096 queries, F=4096 faces (fixed by reference setup_inputs).
#define N_Q 4096
#define N_F 4096
#define FSPLIT 64           // 16 q-blocks x 64 f-splits = 1024 blocks (4/CU, 16 waves/CU)
#define FT (N_F / FSPLIT)   // 64 faces per block

// Fast atan2: degree-15 odd minimax poly on [0,1] (max err ~1e-7 rad),
// v_rcp_f32 division, quadrant fixup via selects. ~18 VALU ops total vs
// ~300 for libm atan2f's accurate-division path.
__device__ __forceinline__ float fast_atan2f(float y, float x) {
    const float pi   = 3.14159265358979f;
    const float pi_2 = 1.57079632679490f;
    float ax = fabsf(x), ay = fabsf(y);
    float mx = fmaxf(ax, ay), mn = fminf(ax, ay);
    float t = mn * __builtin_amdgcn_rcpf(mx);      // t in [0,1]
    t = (mx == 0.0f) ? 0.0f : t;                   // atan2(0,0) -> 0 guard
    float s = t * t;
    float p =              -0.0040540580f;
    p = fmaf(p, s,  0.0218612288f);
    p = fmaf(p, s, -0.0559098861f);
    p = fmaf(p, s,  0.0964200441f);
    p = fmaf(p, s, -0.1390853351f);
    p = fmaf(p, s,  0.1994653599f);
    p = fmaf(p, s, -0.3332985605f);
    p = fmaf(p, s,  0.9999993329f);
    float r = p * t;                               // atan(t), t<=1 -> [0, pi/4]
    r = (ay > ax) ? (pi_2 - r) : r;                // octant -> quadrant I
    r = (x < 0.0f) ? (pi - r) : r;                 // quadrant II
    return copysignf(r, y);                        // lower half-plane
}

__global__ __launch_bounds__(256) void winding_kernel(
    const float* __restrict__ qp,   // [N_Q][3]
    const float* __restrict__ fc,   // [N_F][9]
    float* __restrict__ out)        // [N_Q]
{
    const int q  = blockIdx.x * 256 + threadIdx.x;   // one query per thread
    const int f0 = blockIdx.y * FT;                  // this block's face slice

    const float qx = qp[q * 3 + 0];
    const float qy = qp[q * 3 + 1];
    const float qz = qp[q * 3 + 2];

    float sum = 0.0f;
    #pragma unroll 4
    for (int f = 0; f < FT; ++f) {
        // Wave-uniform address (blockIdx + uniform loop idx) -> scalar loads
        // on the SALU/sL1 pipe; faces (144 KB) are L2-resident.
        const float* v = fc + (size_t)(f0 + f) * 9;
        const float ax = v[0] - qx, ay = v[1] - qy, az = v[2] - qz;
        const float bx = v[3] - qx, by = v[4] - qy, bz = v[5] - qz;
        const float cx = v[6] - qx, cy = v[7] - qy, cz = v[8] - qz;

        // det = a . (b x c)
        const float ux = fmaf(by, cz, -bz * cy);
        const float uy = fmaf(bz, cx, -bx * cz);
        const float uz = fmaf(bx, cy, -by * cx);
        const float det = fmaf(ax, ux, fmaf(ay, uy, az * uz));

        const float na = __builtin_amdgcn_sqrtf(fmaf(ax, ax, fmaf(ay, ay, az * az)));
        const float nb = __builtin_amdgcn_sqrtf(fmaf(bx, bx, fmaf(by, by, bz * bz)));
        const float nc = __builtin_amdgcn_sqrtf(fmaf(cx, cx, fmaf(cy, cy, cz * cz)));

        const float ab = fmaf(ax, bx, fmaf(ay, by, az * bz));
        const float bc = fmaf(bx, cx, fmaf(by, cy, bz * cz));
        const float ac = fmaf(ax, cx, fmaf(ay, cy, az * cz));

        const float denom = fmaf(na * nb, nc, fmaf(bc, na, fmaf(ac, nb, ab * nc)));
        sum += fast_atan2f(det, denom);
    }

    atomicAdd(&out[q], sum * 0.15915494309189535f);  // 1/(2*pi)
}

extern "C" void kernel_launch(void* const* d_in, const int* in_sizes, int n_in,
                              void* d_out, int out_size, void* d_ws, size_t ws_size,
                              hipStream_t stream) {
    const float* qp = (const float*)d_in[0];   // query_points (1,4096,3) f32
    const float* fc = (const float*)d_in[1];   // face_coord   (1,4096,3,3) f32
    float* out = (float*)d_out;                // (1,4096) f32

    // Harness poisons d_out once and never re-poisons between replays:
    // we accumulate with atomics, so zero it ourselves every call.
    hipMemsetAsync(out, 0, (size_t)out_size * sizeof(float), stream);

    dim3 grid(N_Q / 256, FSPLIT);
    dim3 block(256);
    winding_kernel<<<grid, block, 0, stream>>>(qp, fc, out);
}

// Round 3
// 33.149 us; speedup vs baseline: 2.3196x; 1.1620x over previous
//
#include <hip/hip_runtime.h>
#include <math.h>

// B=1, N=4096 queries, F=4096 faces (fixed by reference setup_inputs).
#define N_Q 4096
#define N_F 4096
#define QPT 2                 // queries per thread (ILP + face-load amortization)
#define QBLK (256 * QPT)      // 512 queries per block
#define FSPLIT 128            // 8 q-blocks x 128 f-splits = 1024 blocks (4/CU)
#define FT (N_F / FSPLIT)     // 32 faces per block

// Fast atan2: 6-coeff odd minimax poly on [0,1] (max err ~1e-5 rad),
// v_rcp_f32 division, quadrant fixup via selects.
__device__ __forceinline__ float fast_atan2f(float y, float x) {
    const float pi   = 3.14159265358979f;
    const float pi_2 = 1.57079632679490f;
    float ax = fabsf(x), ay = fabsf(y);
    float mx = fmaxf(ax, ay), mn = fminf(ax, ay);
    float t = mn * __builtin_amdgcn_rcpf(mx);      // t in [0,1]
    t = (mx == 0.0f) ? 0.0f : t;                   // atan2(0,0) -> 0 guard
    float s = t * t;
    float p =              -0.0117212f;
    p = fmaf(p, s,  0.05265332f);
    p = fmaf(p, s, -0.11643287f);
    p = fmaf(p, s,  0.19354346f);
    p = fmaf(p, s, -0.33262347f);
    p = fmaf(p, s,  0.99997726f);
    float r = p * t;                               // atan(t) on [0, pi/4]
    r = (ay > ax) ? (pi_2 - r) : r;                // octant -> quadrant I
    r = (x < 0.0f) ? (pi - r) : r;                 // quadrant II
    return copysignf(r, y);                        // lower half-plane
}

// Per query/face pair solid-angle term.
__device__ __forceinline__ float pair_term(
    float qx, float qy, float qz,
    float v0, float v1, float v2, float v3, float v4,
    float v5, float v6, float v7, float v8)
{
    const float ax = v0 - qx, ay = v1 - qy, az = v2 - qz;
    const float bx = v3 - qx, by = v4 - qy, bz = v5 - qz;
    const float cx = v6 - qx, cy = v7 - qy, cz = v8 - qz;

    const float ux = fmaf(by, cz, -bz * cy);
    const float uy = fmaf(bz, cx, -bx * cz);
    const float uz = fmaf(bx, cy, -by * cx);
    const float det = fmaf(ax, ux, fmaf(ay, uy, az * uz));

    const float na = __builtin_amdgcn_sqrtf(fmaf(ax, ax, fmaf(ay, ay, az * az)));
    const float nb = __builtin_amdgcn_sqrtf(fmaf(bx, bx, fmaf(by, by, bz * bz)));
    const float nc = __builtin_amdgcn_sqrtf(fmaf(cx, cx, fmaf(cy, cy, cz * cz)));

    const float ab = fmaf(ax, bx, fmaf(ay, by, az * bz));
    const float bc = fmaf(bx, cx, fmaf(by, cy, bz * cz));
    const float ac = fmaf(ax, cx, fmaf(ay, cy, az * cz));

    const float denom = fmaf(na * nb, nc, fmaf(bc, na, fmaf(ac, nb, ab * nc)));
    return fast_atan2f(det, denom);
}

__global__ __launch_bounds__(256) void winding_kernel(
    const float* __restrict__ qp,   // [N_Q][3]
    const float* __restrict__ fc,   // [N_F][9]
    float* __restrict__ out)        // [N_Q]
{
    const int q0 = blockIdx.x * QBLK + threadIdx.x;  // query 0
    const int q1 = q0 + 256;                         // query 1
    const int f0 = blockIdx.y * FT;                  // this block's face slice

    const float q0x = qp[q0 * 3 + 0], q0y = qp[q0 * 3 + 1], q0z = qp[q0 * 3 + 2];
    const float q1x = qp[q1 * 3 + 0], q1y = qp[q1 * 3 + 1], q1z = qp[q1 * 3 + 2];

    float s0 = 0.0f, s1 = 0.0f;
    #pragma unroll 4
    for (int f = 0; f < FT; ++f) {
        // Wave-uniform address -> scalar loads; faces (144 KB) are L2-resident.
        const float* v = fc + (size_t)(f0 + f) * 9;
        const float v0 = v[0], v1 = v[1], v2 = v[2];
        const float v3 = v[3], v4 = v[4], v5 = v[5];
        const float v6 = v[6], v7 = v[7], v8 = v[8];

        s0 += pair_term(q0x, q0y, q0z, v0, v1, v2, v3, v4, v5, v6, v7, v8);
        s1 += pair_term(q1x, q1y, q1z, v0, v1, v2, v3, v4, v5, v6, v7, v8);
    }

    const float c = 0.15915494309189535f;  // 1/(2*pi)
    atomicAdd(&out[q0], s0 * c);
    atomicAdd(&out[q1], s1 * c);
}

extern "C" void kernel_launch(void* const* d_in, const int* in_sizes, int n_in,
                              void* d_out, int out_size, void* d_ws, size_t ws_size,
                              hipStream_t stream) {
    const float* qp = (const float*)d_in[0];   // query_points (1,4096,3) f32
    const float* fc = (const float*)d_in[1];   // face_coord   (1,4096,3,3) f32
    float* out = (float*)d_out;                // (1,4096) f32

    // Harness poisons d_out once and never re-poisons between replays:
    // we accumulate with atomics, so zero it ourselves every call.
    hipMemsetAsync(out, 0, (size_t)out_size * sizeof(float), stream);

    dim3 grid(N_Q / QBLK, FSPLIT);
    dim3 block(256);
    winding_kernel<<<grid, block, 0, stream>>>(qp, fc, out);
}